// Round 1
// baseline (426.418 us; speedup 1.0000x reference)
//
#include <hip/hip_runtime.h>
#include <stdint.h>

typedef unsigned short u16;
typedef __bf16 bf16x8 __attribute__((ext_vector_type(8)));
typedef float f32x4 __attribute__((ext_vector_type(4)));

// Problem constants: T=1024, B=32, E=512, HEADS=8, KEYD=16, HEAD=64, MEM_SLOTS=8, TOPK=3

__device__ __forceinline__ u16 f2b(float f) {
  union { float f; uint32_t u; } v; v.f = f;
  return (u16)((v.u + 0x7FFFu + ((v.u >> 16) & 1u)) >> 16);
}
__device__ __forceinline__ float b2f(u16 h) {
  union { uint32_t u; float f; } v; v.u = ((uint32_t)h) << 16; return v.f;
}

// ---------------- converts ----------------
// W_in (512x512) -> WinT (N-major: [n][k]) bf16
__global__ void k_conv_win(const float* __restrict__ W, u16* __restrict__ Wt) {
  int idx = blockIdx.x * 256 + threadIdx.x;   // 262144
  int k = idx >> 9, n = idx & 511;
  Wt[n * 512 + k] = f2b(W[idx]);
}
// Wk (512x128), Wq (512x128) -> WkqT (256x512 bf16, rows 0-127 = Wk cols, 128-255 = Wq cols); bkq = [bk;bq]
__global__ void k_conv_wkq(const float* __restrict__ Wk, const float* __restrict__ Wq,
                           const float* __restrict__ bk, const float* __restrict__ bq,
                           u16* __restrict__ Wt, float* __restrict__ bkq) {
  int idx = blockIdx.x * 256 + threadIdx.x;   // 131072
  if (idx < 65536) {
    int k = idx >> 7, n = idx & 127;
    Wt[n * 512 + k] = f2b(Wk[idx]);
  } else {
    int j = idx - 65536;
    int k = j >> 7, n = j & 127;
    Wt[(128 + n) * 512 + k] = f2b(Wq[j]);
  }
  if (idx < 128) bkq[idx] = bk[idx];
  else if (idx < 256) bkq[idx] = bq[idx - 128];
}
__global__ void k_tanh_mem(const float* __restrict__ mem, float* __restrict__ tm) {
  int idx = blockIdx.x * 256 + threadIdx.x;   // 131072
  tm[idx] = tanhf(mem[idx]);
}

// ---------------- bf16 MFMA GEMM: C[M,N] = A[M,K] @ Bt[N,K]^T + bias ----------------
// AMODE 0: A is bf16 row-major MxK. AMODE 1: A is f32 'key' (T,B,E); logical row r = b*1024+t.
template<int AMODE>
__global__ __launch_bounds__(256) void gemm_kernel(
    const void* __restrict__ Ap, const u16* __restrict__ Bt,
    const float* __restrict__ bias, u16* __restrict__ C,
    const int M, const int N, const int K)
{
  __shared__ u16 As[128 * 40];   // 32 cols padded to 40 (80B rows: 2-way banks = free)
  __shared__ u16 Bs[128 * 40];
  const int tid = threadIdx.x;
  const int m0 = blockIdx.x * 128;
  const int n0 = blockIdx.y * 128;
  const int lane = tid & 63;
  const int wid = tid >> 6;
  const int wm = (wid >> 1) * 64;
  const int wn = (wid & 1) * 64;

  f32x4 acc[4][4];
  #pragma unroll
  for (int i = 0; i < 4; ++i)
    #pragma unroll
    for (int j = 0; j < 4; ++j) acc[i][j] = (f32x4){0.f, 0.f, 0.f, 0.f};

  const int nk = K >> 5;
  for (int kt = 0; kt < nk; ++kt) {
    const int k0 = kt << 5;
    __syncthreads();
    #pragma unroll
    for (int cc = 0; cc < 2; ++cc) {
      const int chunk = tid * 2 + cc;       // 0..511
      const int row = chunk >> 2;           // 0..127
      const int off = (chunk & 3) * 8;      // 0,8,16,24
      if (AMODE == 0) {
        const u16* A = (const u16*)Ap;
        uint4 va = *(const uint4*)(A + (size_t)(m0 + row) * K + k0 + off);
        *(uint4*)(As + row * 40 + off) = va;
      } else {
        const float* A = (const float*)Ap;
        const int r = m0 + row;
        const int bb = r >> 10, t = r & 1023;
        const float* src = A + ((size_t)t * 32 + bb) * 512 + k0 + off;
        float4 lo = *(const float4*)src;
        float4 hi = *(const float4*)(src + 4);
        uint4 o;
        o.x = (uint32_t)f2b(lo.x) | ((uint32_t)f2b(lo.y) << 16);
        o.y = (uint32_t)f2b(lo.z) | ((uint32_t)f2b(lo.w) << 16);
        o.z = (uint32_t)f2b(hi.x) | ((uint32_t)f2b(hi.y) << 16);
        o.w = (uint32_t)f2b(hi.z) | ((uint32_t)f2b(hi.w) << 16);
        *(uint4*)(As + row * 40 + off) = o;
      }
      uint4 vb = *(const uint4*)(Bt + (size_t)(n0 + row) * K + k0 + off);
      *(uint4*)(Bs + row * 40 + off) = vb;
    }
    __syncthreads();
    const int r = lane & 15;
    const int kb = (lane >> 4) * 8;
    bf16x8 af[4], bfr[4];
    #pragma unroll
    for (int i = 0; i < 4; ++i) {
      af[i]  = *(const bf16x8*)(As + (wm + i * 16 + r) * 40 + kb);
      bfr[i] = *(const bf16x8*)(Bs + (wn + i * 16 + r) * 40 + kb);
    }
    #pragma unroll
    for (int i = 0; i < 4; ++i)
      #pragma unroll
      for (int j = 0; j < 4; ++j)
        acc[i][j] = __builtin_amdgcn_mfma_f32_16x16x32_bf16(af[i], bfr[j], acc[i][j], 0, 0, 0);
  }
  const int cl = lane & 15;
  const int rl = (lane >> 4) * 4;
  #pragma unroll
  for (int j = 0; j < 4; ++j) {
    const int col = n0 + wn + j * 16 + cl;
    const float bsv = bias[col];
    #pragma unroll
    for (int i = 0; i < 4; ++i) {
      #pragma unroll
      for (int rr = 0; rr < 4; ++rr) {
        const int row = m0 + wm + i * 16 + rl + rr;
        C[(size_t)row * N + col] = f2b(acc[i][j][rr] + bsv);
      }
    }
  }
}

// ---------------- gi_pre[b,e] = mean_t relu(w_rep[e]*x[b,t,e]) ----------------
__global__ void k_gipre(const u16* __restrict__ x, const float* __restrict__ w_rep,
                        float* __restrict__ gi_pre) {
  int b = blockIdx.x;
  int e = blockIdx.y * 256 + threadIdx.x;
  float w = w_rep[e];
  float acc = 0.f;
  const u16* base = x + ((size_t)b << 19) + e;
  for (int t = 0; t < 1024; ++t)
    acc += fmaxf(w * b2f(base[(size_t)t << 9]), 0.f);
  gi_pre[b * 512 + e] = acc * (1.f / 1024.f);
}

// ---------------- memory<-token attention, top-3, per (b,h) block ----------------
__global__ __launch_bounds__(256) void k_mem_attn(
    const float* __restrict__ memory, const float* __restrict__ Wq,
    const float* __restrict__ bq, const u16* __restrict__ kq,
    const u16* __restrict__ x, const float* __restrict__ Wv,
    const float* __restrict__ bvv, float* __restrict__ att)
{
  const int b = blockIdx.x, h = blockIdx.y;
  const int tid = threadIdx.x;
  __shared__ float mem_s[4096];
  __shared__ u16   kh[1024 * 20];
  __shared__ float qm[128];
  __shared__ float sc[1024];
  __shared__ float rv[256];
  __shared__ int   ri[256];
  __shared__ float tmp3[192];
  __shared__ u16   xr_s[1536];
  __shared__ float topv[3];
  __shared__ int   topi[3];
  __shared__ float ssum;

  for (int i = tid; i < 4096; i += 256) mem_s[i] = memory[(size_t)b * 4096 + i];
  #pragma unroll
  for (int c = 0; c < 16; ++c) {
    int chunk = c * 256 + tid;          // 4096 chunks of 4 u16
    int t = chunk >> 2, q = chunk & 3;
    const u16* src = kq + ((size_t)(b * 1024 + t)) * 256 + h * 16 + q * 4;
    *(uint2*)(kh + t * 20 + q * 4) = *(const uint2*)src;
  }
  __syncthreads();
  if (tid < 128) {
    int s = tid >> 4, d = tid & 15;
    float a = bq[h * 16 + d];
    for (int e = 0; e < 512; ++e) a += mem_s[s * 512 + e] * Wq[(size_t)e * 128 + h * 16 + d];
    qm[tid] = a;
  }
  __syncthreads();

  for (int s = 0; s < 8; ++s) {
    for (int tt = 0; tt < 4; ++tt) {
      int t = tt * 256 + tid;
      float a = 0.f;
      #pragma unroll
      for (int d = 0; d < 16; ++d) a += qm[s * 16 + d] * b2f(kh[t * 20 + d]);
      sc[t] = a;
    }
    __syncthreads();
    for (int pass = 0; pass < 3; ++pass) {
      float bv_ = -1e38f; int bi_ = 1 << 30;
      for (int tt = 0; tt < 4; ++tt) {
        int t = tt * 256 + tid;
        float v = sc[t];
        if (v > bv_ || (v == bv_ && t < bi_)) { bv_ = v; bi_ = t; }
      }
      rv[tid] = bv_; ri[tid] = bi_;
      __syncthreads();
      for (int off = 128; off > 0; off >>= 1) {
        if (tid < off) {
          float ov = rv[tid + off]; int oi = ri[tid + off];
          if (ov > rv[tid] || (ov == rv[tid] && oi < ri[tid])) { rv[tid] = ov; ri[tid] = oi; }
        }
        __syncthreads();
      }
      if (tid == 0) { topv[pass] = rv[0]; topi[pass] = ri[0]; }
      __syncthreads();
      if (pass == 0) {
        float mx = topv[0];
        float se = 0.f;
        for (int tt = 0; tt < 4; ++tt) se += __expf(sc[tt * 256 + tid] - mx);
        rv[tid] = se;
        __syncthreads();
        for (int off = 128; off > 0; off >>= 1) {
          if (tid < off) rv[tid] += rv[tid + off];
          __syncthreads();
        }
        if (tid == 0) ssum = rv[0];
        __syncthreads();
      }
      if (tid == 0) sc[topi[pass]] = -1e38f;
      __syncthreads();
    }
    // stage the 3 selected token rows of x
    for (int i = tid; i < 1536; i += 256) {
      int j = i >> 9, e = i & 511;
      xr_s[i] = x[((size_t)(b * 1024 + topi[j])) * 512 + e];
    }
    __syncthreads();
    if (tid < 192) {
      int j = tid >> 6, c = tid & 63;
      float p = __expf(topv[j] - topv[0]) / ssum;
      float a = bvv[h * 64 + c];
      for (int e = 0; e < 512; ++e)
        a += b2f(xr_s[j * 512 + e]) * Wv[(size_t)e * 512 + h * 64 + c];
      tmp3[tid] = p * a;
    }
    __syncthreads();
    if (tid < 64)
      att[((size_t)(b * 8 + s)) * 512 + h * 64 + tid] = tmp3[tid] + tmp3[64 + tid] + tmp3[128 + tid];
    __syncthreads();
  }
}

// ---------------- LN1 + MLP + LN2 per (b,slot) ----------------
__global__ __launch_bounds__(256) void k_mem_lnmlp(
    const float* __restrict__ memory, const float* __restrict__ att,
    const float* __restrict__ g1, const float* __restrict__ be1,
    const float* __restrict__ W_mlp, const float* __restrict__ b_mlp,
    const float* __restrict__ g2, const float* __restrict__ be2,
    float* __restrict__ nm_ln)
{
  const int b = blockIdx.x, s = blockIdx.y;
  const int tid = threadIdx.x;
  __shared__ float m_s[512];
  __shared__ float r1[256], r2[256];
  const size_t base = (size_t)(b * 8 + s) * 512;
  float v0 = memory[base + tid] + att[base + tid];
  float v1 = memory[base + 256 + tid] + att[base + 256 + tid];
  r1[tid] = v0 + v1; r2[tid] = v0 * v0 + v1 * v1;
  __syncthreads();
  for (int off = 128; off > 0; off >>= 1) {
    if (tid < off) { r1[tid] += r1[tid + off]; r2[tid] += r2[tid + off]; }
    __syncthreads();
  }
  float mu = r1[0] * (1.f / 512.f);
  float var = r2[0] * (1.f / 512.f) - mu * mu;
  float rs = rsqrtf(var + 1e-5f);
  __syncthreads();
  m_s[tid]       = (v0 - mu) * rs * g1[tid] + be1[tid];
  m_s[tid + 256] = (v1 - mu) * rs * g1[tid + 256] + be1[tid + 256];
  __syncthreads();
  float d0 = b_mlp[tid], d1 = b_mlp[tid + 256];
  for (int c4 = 0; c4 < 128; ++c4) {
    float4 m4 = *(const float4*)&m_s[c4 * 4];
    const float* w = W_mlp + (size_t)c4 * 4 * 512;
    d0 += m4.x * w[tid];        d1 += m4.x * w[tid + 256];
    d0 += m4.y * w[512 + tid];  d1 += m4.y * w[512 + tid + 256];
    d0 += m4.z * w[1024 + tid]; d1 += m4.z * w[1024 + tid + 256];
    d0 += m4.w * w[1536 + tid]; d1 += m4.w * w[1536 + tid + 256];
  }
  float h0 = m_s[tid] + fmaxf(d0, 0.f);
  float h1 = m_s[tid + 256] + fmaxf(d1, 0.f);
  __syncthreads();
  r1[tid] = h0 + h1; r2[tid] = h0 * h0 + h1 * h1;
  __syncthreads();
  for (int off = 128; off > 0; off >>= 1) {
    if (tid < off) { r1[tid] += r1[tid + off]; r2[tid] += r2[tid + off]; }
    __syncthreads();
  }
  float mu2 = r1[0] * (1.f / 512.f);
  float var2 = r2[0] * (1.f / 512.f) - mu2 * mu2;
  float rs2 = rsqrtf(var2 + 1e-5f);
  nm_ln[base + tid]       = (h0 - mu2) * rs2 * g2[tid] + be2[tid];
  nm_ln[base + 256 + tid] = (h1 - mu2) * rs2 * g2[tid + 256] + be2[tid + 256];
}

// ---------------- gi = gi_pre @ W_ig + b_ig ----------------
__global__ void k_gi_kernel(const float* __restrict__ gi_pre, const float* __restrict__ W_ig,
                            const float* __restrict__ b_ig, float* __restrict__ gi)
{
  int b = blockIdx.x; int tid = threadIdx.x;
  int n = blockIdx.y * 256 + tid;
  __shared__ float gp[512];
  gp[tid] = gi_pre[b * 512 + tid];
  gp[tid + 256] = gi_pre[b * 512 + 256 + tid];
  __syncthreads();
  float a = b_ig[n];
  for (int e4 = 0; e4 < 128; ++e4) {
    float4 g4 = *(const float4*)&gp[e4 * 4];
    const float* w = W_ig + (size_t)e4 * 4 * 1024 + n;
    a += g4.x * w[0] + g4.y * w[1024] + g4.z * w[2048] + g4.w * w[3072];
  }
  gi[b * 1024 + n] = a;
}

// ---------------- gm[b,s,n] = tanh(memory[b,s]) @ W_mg[s] + b_mg[s] ----------------
__global__ __launch_bounds__(256) void k_gm_kernel(
    const float* __restrict__ tm, const float* __restrict__ W_mg,
    const float* __restrict__ b_mg, float* __restrict__ gm)
{
  int s = blockIdx.x;
  int n = blockIdx.y * 256 + threadIdx.x;
  int b0 = blockIdx.z * 8;
  float acc[8];
  #pragma unroll
  for (int i = 0; i < 8; ++i) acc[i] = 0.f;
  const float* wp = W_mg + (size_t)s * 512 * 1024 + n;
  for (int e4 = 0; e4 < 128; ++e4) {
    float w0 = wp[(size_t)(e4 * 4 + 0) * 1024];
    float w1 = wp[(size_t)(e4 * 4 + 1) * 1024];
    float w2 = wp[(size_t)(e4 * 4 + 2) * 1024];
    float w3 = wp[(size_t)(e4 * 4 + 3) * 1024];
    #pragma unroll
    for (int i = 0; i < 8; ++i) {
      const float4 t4 = *(const float4*)(tm + ((size_t)((b0 + i) * 8 + s)) * 512 + e4 * 4);
      acc[i] += t4.x * w0 + t4.y * w1 + t4.z * w2 + t4.w * w3;
    }
  }
  float bm = b_mg[s * 1024 + n];
  #pragma unroll
  for (int i = 0; i < 8; ++i)
    gm[((size_t)((b0 + i) * 8 + s)) * 1024 + n] = acc[i] + bm;
}

// ---------------- gating ----------------
__global__ void k_gate_kernel(const float* __restrict__ gi, const float* __restrict__ gm,
                              const float* __restrict__ nm_ln, const float* __restrict__ memory,
                              const float* __restrict__ fbias, const float* __restrict__ ibias,
                              float* __restrict__ nmem)
{
  int idx = blockIdx.x * 256 + threadIdx.x;   // 131072
  int b = idx >> 12; int rem = idx & 4095; int s = rem >> 9; int e = rem & 511;
  float fb = fbias[0], ib = ibias[0];
  size_t gidx = (size_t)(b * 8 + s) * 1024;
  float ing = 1.f / (1.f + __expf(-(gi[b * 1024 + e] + gm[gidx + e] + ib)));
  float fg  = 1.f / (1.f + __expf(-(gi[b * 1024 + 512 + e] + gm[gidx + 512 + e] + fb)));
  nmem[idx] = ing * tanhf(nm_ln[idx]) + fg * memory[idx];
}

// ---------------- k_mem / v_mem from new memory ----------------
__global__ __launch_bounds__(256) void k_kvmem_kernel(
    const float* __restrict__ nmem, const float* __restrict__ Wk, const float* __restrict__ bk,
    const float* __restrict__ Wv, const float* __restrict__ bv,
    float* __restrict__ k_mem, float* __restrict__ v_mem)
{
  int b = blockIdx.x, chunk = blockIdx.y;   // 10 chunks
  int tid = threadIdx.x;
  __shared__ float nm[4096];
  for (int i = tid; i < 1024; i += 256)
    *(float4*)&nm[i * 4] = *(const float4*)&nmem[(size_t)b * 4096 + i * 4];
  __syncthreads();
  if (chunk < 2) {
    for (int r = 0; r < 2; ++r) {
      int o = chunk * 512 + r * 256 + tid;   // 0..1023
      int s = o >> 7, j = o & 127;
      float a = bk[j];
      for (int e4 = 0; e4 < 128; ++e4) {
        float4 m4 = *(const float4*)&nm[s * 512 + e4 * 4];
        const float* w = Wk + (size_t)e4 * 4 * 128 + j;
        a += m4.x * w[0] + m4.y * w[128] + m4.z * w[256] + m4.w * w[384];
      }
      k_mem[(size_t)b * 1024 + o] = a;
    }
  } else {
    int cv = chunk - 2;                      // slot
    for (int r = 0; r < 2; ++r) {
      int c = r * 256 + tid;
      float a = bv[c];
      for (int e4 = 0; e4 < 128; ++e4) {
        float4 m4 = *(const float4*)&nm[cv * 512 + e4 * 4];
        const float* w = Wv + (size_t)e4 * 4 * 512 + c;
        a += m4.x * w[0] + m4.y * w[512] + m4.z * w[1024] + m4.w * w[1536];
      }
      v_mem[((size_t)b * 8 + cv) * 512 + c] = a;
    }
  }
}

// ---------------- final broadcast attention -> out (T,B,E) ----------------
__global__ __launch_bounds__(256) void k_out_attn(
    const u16* __restrict__ kq, const float* __restrict__ k_mem,
    const float* __restrict__ v_mem, float* __restrict__ out)
{
  int b = blockIdx.x, tc = blockIdx.y;
  int tid = threadIdx.x;
  __shared__ float km[1024];
  __shared__ float vm[4096];
  __shared__ float pr[4096];   // [tt][h][s]
  for (int i = tid; i < 1024; i += 256) km[i] = k_mem[(size_t)b * 1024 + i];
  for (int i = tid; i < 4096; i += 256) vm[i] = v_mem[(size_t)b * 4096 + i];
  __syncthreads();
  #pragma unroll
  for (int pi = 0; pi < 2; ++pi) {
    int p = pi * 256 + tid;
    int tt = p >> 3, hh = p & 7;
    int t = tc * 64 + tt;
    const u16* qrow = kq + ((size_t)(b * 1024 + t)) * 256 + 128 + hh * 16;
    float q[16];
    #pragma unroll
    for (int d = 0; d < 16; ++d) q[d] = b2f(qrow[d]);
    float s8[8]; float mx = -1e38f;
    #pragma unroll
    for (int s = 0; s < 8; ++s) {
      float a = 0.f;
      #pragma unroll
      for (int d = 0; d < 16; ++d) a += q[d] * km[s * 128 + hh * 16 + d];
      s8[s] = a; mx = fmaxf(mx, a);
    }
    float se = 0.f;
    #pragma unroll
    for (int s = 0; s < 8; ++s) { s8[s] = __expf(s8[s] - mx); se += s8[s]; }
    float inv = 1.f / se;
    #pragma unroll
    for (int s = 0; s < 8; ++s) pr[(tt * 8 + hh) * 8 + s] = s8[s] * inv;
  }
  __syncthreads();
  for (int oi = 0; oi < 128; ++oi) {
    int o = oi * 256 + tid;
    int tt = o >> 9, c = o & 511, hh = c >> 6;
    float a = 0.f;
    #pragma unroll
    for (int s = 0; s < 8; ++s) a += pr[(tt * 8 + hh) * 8 + s] * vm[s * 512 + c];
    int t = tc * 64 + tt;
    out[((size_t)t * 32 + b) * 512 + c] = a;
  }
}

extern "C" void kernel_launch(void* const* d_in, const int* in_sizes, int n_in,
                              void* d_out, int out_size, void* d_ws, size_t ws_size,
                              hipStream_t stream) {
  (void)in_sizes; (void)n_in; (void)out_size; (void)ws_size;
  const float* key   = (const float*)d_in[1];
  const float* memory= (const float*)d_in[2];
  const float* W_in  = (const float*)d_in[3];
  const float* b_in  = (const float*)d_in[4];
  const float* Wq    = (const float*)d_in[5];
  const float* bq    = (const float*)d_in[6];
  const float* Wk    = (const float*)d_in[7];
  const float* bk    = (const float*)d_in[8];
  const float* Wv    = (const float*)d_in[9];
  const float* bv    = (const float*)d_in[10];
  const float* W_mlp = (const float*)d_in[11];
  const float* b_mlp = (const float*)d_in[12];
  const float* g1    = (const float*)d_in[13];
  const float* be1   = (const float*)d_in[14];
  const float* g2    = (const float*)d_in[15];
  const float* be2   = (const float*)d_in[16];
  const float* w_rep = (const float*)d_in[17];
  const float* W_ig  = (const float*)d_in[18];
  const float* b_ig  = (const float*)d_in[19];
  const float* W_mg  = (const float*)d_in[20];
  const float* b_mg  = (const float*)d_in[21];
  const float* fbias = (const float*)d_in[22];
  const float* ibias = (const float*)d_in[23];
  float* out = (float*)d_out;

  char* p = (char*)d_ws;
  auto alloc = [&](size_t bytes) { char* r = p; p += (bytes + 255) & ~(size_t)255; return r; };
  u16* x       = (u16*)alloc(33554432);    // x bf16 (B,T,E)
  u16* kq      = (u16*)alloc(16777216);    // [k | q] bf16 (B*T, 256)
  u16* WinT    = (u16*)alloc(524288);
  u16* WkqT    = (u16*)alloc(262144);
  float* bkq   = (float*)alloc(1024);
  float* gi_pre= (float*)alloc(65536);
  float* gi    = (float*)alloc(131072);
  float* gm    = (float*)alloc(1048576);
  float* att   = (float*)alloc(524288);
  float* nm_ln = (float*)alloc(524288);
  float* nmem  = (float*)alloc(524288);
  float* kmem  = (float*)alloc(131072);
  float* vmem  = (float*)alloc(524288);
  float* tm    = (float*)alloc(524288);

  k_conv_win<<<1024, 256, 0, stream>>>(W_in, WinT);
  k_conv_wkq<<<512, 256, 0, stream>>>(Wk, Wq, bk, bq, WkqT, bkq);
  k_tanh_mem<<<512, 256, 0, stream>>>(memory, tm);
  gemm_kernel<1><<<dim3(256, 4), 256, 0, stream>>>(key, WinT, b_in, x, 32768, 512, 512);
  gemm_kernel<0><<<dim3(256, 2), 256, 0, stream>>>(x, WkqT, bkq, kq, 32768, 256, 512);
  k_gipre<<<dim3(32, 2), 256, 0, stream>>>(x, w_rep, gi_pre);
  k_mem_attn<<<dim3(32, 8), 256, 0, stream>>>(memory, Wq, bq, kq, x, Wv, bv, att);
  k_mem_lnmlp<<<dim3(32, 8), 256, 0, stream>>>(memory, att, g1, be1, W_mlp, b_mlp, g2, be2, nm_ln);
  k_gi_kernel<<<dim3(32, 4), 256, 0, stream>>>(gi_pre, W_ig, b_ig, gi);
  k_gm_kernel<<<dim3(8, 4, 4), 256, 0, stream>>>(tm, W_mg, b_mg, gm);
  k_gate_kernel<<<512, 256, 0, stream>>>(gi, gm, nm_ln, memory, fbias, ibias, nmem);
  k_kvmem_kernel<<<dim3(32, 10), 256, 0, stream>>>(nmem, Wk, bk, Wv, bv, kmem, vmem);
  k_out_attn<<<dim3(32, 16), 256, 0, stream>>>(kq, kmem, vmem, out);
}

// Round 2
// 292.722 us; speedup vs baseline: 1.4567x; 1.4567x over previous
//
#include <hip/hip_runtime.h>
#include <stdint.h>

typedef unsigned short u16;
typedef __bf16 bf16x8 __attribute__((ext_vector_type(8)));
typedef float f32x4 __attribute__((ext_vector_type(4)));

// Problem constants: T=1024, B=32, E=512, HEADS=8, KEYD=16, HEAD=64, MEM_SLOTS=8, TOPK=3

__device__ __forceinline__ u16 f2b(float f) {
  union { float f; uint32_t u; } v; v.f = f;
  return (u16)((v.u + 0x7FFFu + ((v.u >> 16) & 1u)) >> 16);
}
__device__ __forceinline__ float b2f(u16 h) {
  union { uint32_t u; float f; } v; v.u = ((uint32_t)h) << 16; return v.f;
}
__device__ __forceinline__ void gload_lds16(const void* g, void* l) {
  __builtin_amdgcn_global_load_lds(
      (const __attribute__((address_space(1))) unsigned int*)g,
      (__attribute__((address_space(3))) unsigned int*)l, 16, 0, 0);
}

// ---------------- converts ----------------
__global__ void k_conv_win(const float* __restrict__ W, u16* __restrict__ Wt) {
  int idx = blockIdx.x * 256 + threadIdx.x;   // 262144
  int k = idx >> 9, n = idx & 511;
  Wt[n * 512 + k] = f2b(W[idx]);
}
__global__ void k_conv_wkq(const float* __restrict__ Wk, const float* __restrict__ Wq,
                           const float* __restrict__ bk, const float* __restrict__ bq,
                           u16* __restrict__ Wt, float* __restrict__ bkq) {
  int idx = blockIdx.x * 256 + threadIdx.x;   // 131072
  if (idx < 65536) {
    int k = idx >> 7, n = idx & 127;
    Wt[n * 512 + k] = f2b(Wk[idx]);
  } else {
    int j = idx - 65536;
    int k = j >> 7, n = j & 127;
    Wt[(128 + n) * 512 + k] = f2b(Wq[j]);
  }
  if (idx < 128) bkq[idx] = bk[idx];
  else if (idx < 256) bkq[idx] = bq[idx - 128];
}
__global__ void k_tanh_mem(const float* __restrict__ mem, float* __restrict__ tm) {
  int idx = blockIdx.x * 256 + threadIdx.x;   // 131072
  tm[idx] = tanhf(mem[idx]);
}

// ---------------- bf16 MFMA GEMM: C[M,N] = A[M,K] @ Bt[N,K]^T + bias ----------------
// AMODE 0: A bf16 row-major, staged via global_load_lds. AMODE 1: A f32 'key' (T,B,E), reg-convert.
template<int AMODE>
__global__ __launch_bounds__(256) void gemm_kernel(
    const void* __restrict__ Ap, const u16* __restrict__ Bt,
    const float* __restrict__ bias, u16* __restrict__ C,
    const int M, const int N, const int K)
{
  __shared__ u16 As[128 * 32];
  __shared__ u16 Bs[128 * 32];
  const int tid = threadIdx.x;
  const int m0 = blockIdx.x * 128;
  const int n0 = blockIdx.y * 128;
  const int lane = tid & 63;
  const int wid = tid >> 6;
  const int wm = (wid >> 1) * 64;
  const int wn = (wid & 1) * 64;

  f32x4 acc[4][4];
  #pragma unroll
  for (int i = 0; i < 4; ++i)
    #pragma unroll
    for (int j = 0; j < 4; ++j) acc[i][j] = (f32x4){0.f, 0.f, 0.f, 0.f};

  const int nk = K >> 5;
  for (int kt = 0; kt < nk; ++kt) {
    const int k0 = kt << 5;
    __syncthreads();
    if (AMODE == 0) {
      const u16* A = (const u16*)Ap;
      #pragma unroll
      for (int c = 0; c < 2; ++c) {
        int o = c * 2048 + tid * 8;
        int row = o >> 5, ck = o & 31;
        gload_lds16(A + (size_t)(m0 + row) * K + k0 + ck, As + o);
      }
    } else {
      #pragma unroll
      for (int cc = 0; cc < 2; ++cc) {
        const int chunk = tid * 2 + cc;       // 0..511
        const int row = chunk >> 2;           // 0..127
        const int off = (chunk & 3) * 8;      // 0,8,16,24
        const float* A = (const float*)Ap;
        const int r = m0 + row;
        const int bb = r >> 10, t = r & 1023;
        const float* src = A + ((size_t)t * 32 + bb) * 512 + k0 + off;
        float4 lo = *(const float4*)src;
        float4 hi = *(const float4*)(src + 4);
        uint4 o4;
        o4.x = (uint32_t)f2b(lo.x) | ((uint32_t)f2b(lo.y) << 16);
        o4.y = (uint32_t)f2b(lo.z) | ((uint32_t)f2b(lo.w) << 16);
        o4.z = (uint32_t)f2b(hi.x) | ((uint32_t)f2b(hi.y) << 16);
        o4.w = (uint32_t)f2b(hi.z) | ((uint32_t)f2b(hi.w) << 16);
        *(uint4*)(As + row * 32 + off) = o4;
      }
    }
    #pragma unroll
    for (int c = 0; c < 2; ++c) {
      int o = c * 2048 + tid * 8;
      int row = o >> 5, ck = o & 31;
      gload_lds16(Bt + (size_t)(n0 + row) * K + k0 + ck, Bs + o);
    }
    __syncthreads();
    const int r = lane & 15;
    const int kb = (lane >> 4) * 8;
    bf16x8 af[4], bfr[4];
    #pragma unroll
    for (int i = 0; i < 4; ++i) {
      af[i]  = *(const bf16x8*)(As + (wm + i * 16 + r) * 32 + kb);
      bfr[i] = *(const bf16x8*)(Bs + (wn + i * 16 + r) * 32 + kb);
    }
    #pragma unroll
    for (int i = 0; i < 4; ++i)
      #pragma unroll
      for (int j = 0; j < 4; ++j)
        acc[i][j] = __builtin_amdgcn_mfma_f32_16x16x32_bf16(af[i], bfr[j], acc[i][j], 0, 0, 0);
  }
  const int cl = lane & 15;
  const int rl = (lane >> 4) * 4;
  #pragma unroll
  for (int j = 0; j < 4; ++j) {
    const int col = n0 + wn + j * 16 + cl;
    const float bsv = bias[col];
    #pragma unroll
    for (int i = 0; i < 4; ++i) {
      #pragma unroll
      for (int rr = 0; rr < 4; ++rr) {
        const int row = m0 + wm + i * 16 + rl + rr;
        C[(size_t)row * N + col] = f2b(acc[i][j][rr] + bsv);
      }
    }
  }
}

// ---------------- qm[b,s,h*16+d] = memory[b,s,:] @ Wq + bq ----------------
__global__ __launch_bounds__(256) void k_qm(
    const float* __restrict__ memory, const float* __restrict__ Wq,
    const float* __restrict__ bq, float* __restrict__ qm)
{
  const int b = blockIdx.x, s = blockIdx.y;
  const int tid = threadIdx.x;
  const int col = tid & 127, half = tid >> 7;
  __shared__ float mrow[512];
  __shared__ float part[2][128];
  *(float2*)&mrow[tid * 2] = *(const float2*)&memory[(size_t)(b * 8 + s) * 512 + tid * 2];
  __syncthreads();
  float a = 0.f;
  const int e0 = half * 256;
  for (int e = 0; e < 256; ++e)
    a += mrow[e0 + e] * Wq[(size_t)(e0 + e) * 128 + col];
  part[half][col] = a;
  __syncthreads();
  if (tid < 128)
    qm[(size_t)(b * 8 + s) * 128 + tid] = part[0][tid] + part[1][tid] + bq[tid];
}

// ---------------- scores + top3 + softmax per (b,h,s) ----------------
__global__ __launch_bounds__(256) void k_scores_topk(
    const float* __restrict__ qm, const u16* __restrict__ kq,
    float* __restrict__ p3, int* __restrict__ idx3)
{
  const int b = blockIdx.x, h = blockIdx.y, s = blockIdx.z;
  const int tid = threadIdx.x;
  __shared__ float swv[4];
  __shared__ int   swi[4];
  __shared__ float ssv[4];

  float q[16];
  const float* qp = qm + ((size_t)(b * 8 + s) * 128 + h * 16);
  #pragma unroll
  for (int d = 0; d < 16; ++d) q[d] = qp[d];

  float sc[4];
  #pragma unroll
  for (int j = 0; j < 4; ++j) {
    const int t = j * 256 + tid;
    const u16* kr = kq + ((size_t)(b * 1024 + t)) * 256 + h * 16;
    uint4 v0 = *(const uint4*)kr;
    uint4 v1 = *(const uint4*)(kr + 8);
    const u16* p0 = (const u16*)&v0;
    const u16* p1 = (const u16*)&v1;
    float a = 0.f;
    #pragma unroll
    for (int d = 0; d < 8; ++d) a += q[d] * b2f(p0[d]);
    #pragma unroll
    for (int d = 0; d < 8; ++d) a += q[8 + d] * b2f(p1[d]);
    sc[j] = a;
  }

  int   seli[3];
  float selv[3];
  float ssum = 0.f;
  #pragma unroll
  for (int pass = 0; pass < 3; ++pass) {
    float bv_ = -1e30f; int bi_ = 1 << 30;
    #pragma unroll
    for (int j = 0; j < 4; ++j) {
      const int t = j * 256 + tid;
      bool skip = false;
      for (int k = 0; k < pass; ++k) skip |= (t == seli[k]);
      float v = skip ? -1e30f : sc[j];
      if (v > bv_ || (v == bv_ && t < bi_)) { bv_ = v; bi_ = t; }
    }
    #pragma unroll
    for (int o = 32; o > 0; o >>= 1) {
      float ov = __shfl_xor(bv_, o);
      int   oi = __shfl_xor(bi_, o);
      if (ov > bv_ || (ov == bv_ && oi < bi_)) { bv_ = ov; bi_ = oi; }
    }
    __syncthreads();
    if ((tid & 63) == 0) { swv[tid >> 6] = bv_; swi[tid >> 6] = bi_; }
    __syncthreads();
    float wv = swv[0]; int wi = swi[0];
    #pragma unroll
    for (int w = 1; w < 4; ++w) {
      float ov = swv[w]; int oi = swi[w];
      if (ov > wv || (ov == wv && oi < wi)) { wv = ov; wi = oi; }
    }
    selv[pass] = wv; seli[pass] = wi;

    if (pass == 0) {
      // softmax denominator with m0 = wv
      float se = 0.f;
      #pragma unroll
      for (int j = 0; j < 4; ++j) se += __expf(sc[j] - wv);
      #pragma unroll
      for (int o = 32; o > 0; o >>= 1) se += __shfl_xor(se, o);
      __syncthreads();
      if ((tid & 63) == 0) ssv[tid >> 6] = se;
      __syncthreads();
      ssum = ssv[0] + ssv[1] + ssv[2] + ssv[3];
    }
  }

  if (tid == 0) {
    const float m0 = selv[0];
    const float inv = 1.f / ssum;
    const size_t base = (size_t)(b * 64 + h * 8 + s);
    float sp = 0.f;
    #pragma unroll
    for (int j = 0; j < 3; ++j) {
      float pj = __expf(selv[j] - m0) * inv;
      p3[base * 4 + j] = pj;
      idx3[base * 3 + j] = seli[j];
      sp += pj;
    }
    p3[base * 4 + 3] = sp;
  }
}

// ---------------- att[b,s,:] = (sum_j p_j x_j) @ Wv + sp*bv (per head column block) ----------------
__global__ __launch_bounds__(512) void k_attval(
    const u16* __restrict__ x, const float* __restrict__ p3, const int* __restrict__ idx3,
    const float* __restrict__ Wv, const float* __restrict__ bvv, float* __restrict__ att)
{
  const int b = blockIdx.x, s = blockIdx.y;
  const int tid = threadIdx.x;
  const int h = tid >> 6, lane = tid & 63;
  __shared__ float xw[8][512];

  const size_t base = (size_t)(b * 64 + h * 8 + s);
  const float p0 = p3[base * 4 + 0];
  const float p1 = p3[base * 4 + 1];
  const float p2 = p3[base * 4 + 2];
  const float sp = p3[base * 4 + 3];
  const int i0 = idx3[base * 3 + 0];
  const int i1 = idx3[base * 3 + 1];
  const int i2 = idx3[base * 3 + 2];

  const u16* xb = x + ((size_t)b << 19) + lane * 8;
  uint4 a0 = *(const uint4*)(xb + ((size_t)i0 << 9));
  uint4 a1 = *(const uint4*)(xb + ((size_t)i1 << 9));
  uint4 a2 = *(const uint4*)(xb + ((size_t)i2 << 9));
  const u16* e0 = (const u16*)&a0;
  const u16* e1 = (const u16*)&a1;
  const u16* e2 = (const u16*)&a2;
  #pragma unroll
  for (int k = 0; k < 8; ++k)
    xw[h][lane * 8 + k] = p0 * b2f(e0[k]) + p1 * b2f(e1[k]) + p2 * b2f(e2[k]);
  __syncthreads();

  float a = 0.f;
  const float* wp = Wv + tid;
  #pragma unroll 4
  for (int e = 0; e < 512; ++e)
    a += xw[h][e] * wp[(size_t)e << 9];
  att[(size_t)(b * 8 + s) * 512 + tid] = a + sp * bvv[tid];
}

// ---------------- gi partials: gpart[b,ch,e] = sum over 128 tokens of relu(w_rep*x) ----------------
__global__ __launch_bounds__(256) void k_gipre(
    const u16* __restrict__ x, const float* __restrict__ w_rep,
    float* __restrict__ gpart)
{
  const int b = blockIdx.x, ch = blockIdx.y;
  const int tid = threadIdx.x;
  const int e8 = tid & 63, tp = tid >> 6;
  float w[8], acc[8];
  #pragma unroll
  for (int k = 0; k < 8; ++k) { w[k] = w_rep[e8 * 8 + k]; acc[k] = 0.f; }
  const int t0 = ch * 128 + tp * 32;
  for (int tt = 0; tt < 32; ++tt) {
    uint4 v = *(const uint4*)(x + ((size_t)(b * 1024 + t0 + tt) << 9) + e8 * 8);
    const u16* pv = (const u16*)&v;
    #pragma unroll
    for (int k = 0; k < 8; ++k) acc[k] += fmaxf(w[k] * b2f(pv[k]), 0.f);
  }
  __shared__ float ps[4][512];
  #pragma unroll
  for (int k = 0; k < 8; ++k) ps[tp][e8 * 8 + k] = acc[k];
  __syncthreads();
  #pragma unroll
  for (int r = 0; r < 2; ++r) {
    int e = r * 256 + tid;
    gpart[(size_t)(b * 8 + ch) * 512 + e] = ps[0][e] + ps[1][e] + ps[2][e] + ps[3][e];
  }
}

// ---------------- LN1 + MLP + LN2 per (b,slot) ----------------
__global__ __launch_bounds__(256) void k_mem_lnmlp(
    const float* __restrict__ memory, const float* __restrict__ att,
    const float* __restrict__ g1, const float* __restrict__ be1,
    const float* __restrict__ W_mlp, const float* __restrict__ b_mlp,
    const float* __restrict__ g2, const float* __restrict__ be2,
    float* __restrict__ nm_ln)
{
  const int b = blockIdx.x, s = blockIdx.y;
  const int tid = threadIdx.x;
  __shared__ float m_s[512];
  __shared__ float r1[256], r2[256];
  const size_t base = (size_t)(b * 8 + s) * 512;
  float v0 = memory[base + tid] + att[base + tid];
  float v1 = memory[base + 256 + tid] + att[base + 256 + tid];
  r1[tid] = v0 + v1; r2[tid] = v0 * v0 + v1 * v1;
  __syncthreads();
  for (int off = 128; off > 0; off >>= 1) {
    if (tid < off) { r1[tid] += r1[tid + off]; r2[tid] += r2[tid + off]; }
    __syncthreads();
  }
  float mu = r1[0] * (1.f / 512.f);
  float var = r2[0] * (1.f / 512.f) - mu * mu;
  float rs = rsqrtf(var + 1e-5f);
  __syncthreads();
  m_s[tid]       = (v0 - mu) * rs * g1[tid] + be1[tid];
  m_s[tid + 256] = (v1 - mu) * rs * g1[tid + 256] + be1[tid + 256];
  __syncthreads();
  float d0 = b_mlp[tid], d1 = b_mlp[tid + 256];
  for (int c4 = 0; c4 < 128; ++c4) {
    float4 m4 = *(const float4*)&m_s[c4 * 4];
    const float* w = W_mlp + (size_t)c4 * 4 * 512;
    d0 += m4.x * w[tid];        d1 += m4.x * w[tid + 256];
    d0 += m4.y * w[512 + tid];  d1 += m4.y * w[512 + tid + 256];
    d0 += m4.z * w[1024 + tid]; d1 += m4.z * w[1024 + tid + 256];
    d0 += m4.w * w[1536 + tid]; d1 += m4.w * w[1536 + tid + 256];
  }
  float h0 = m_s[tid] + fmaxf(d0, 0.f);
  float h1 = m_s[tid + 256] + fmaxf(d1, 0.f);
  __syncthreads();
  r1[tid] = h0 + h1; r2[tid] = h0 * h0 + h1 * h1;
  __syncthreads();
  for (int off = 128; off > 0; off >>= 1) {
    if (tid < off) { r1[tid] += r1[tid + off]; r2[tid] += r2[tid + off]; }
    __syncthreads();
  }
  float mu2 = r1[0] * (1.f / 512.f);
  float var2 = r2[0] * (1.f / 512.f) - mu2 * mu2;
  float rs2 = rsqrtf(var2 + 1e-5f);
  nm_ln[base + tid]       = (h0 - mu2) * rs2 * g2[tid] + be2[tid];
  nm_ln[base + 256 + tid] = (h1 - mu2) * rs2 * g2[tid + 256] + be2[tid + 256];
}

// ---------------- gi = (sum gpart / 1024) @ W_ig + b_ig ----------------
__global__ void k_gi_kernel(const float* __restrict__ gpart, const float* __restrict__ W_ig,
                            const float* __restrict__ b_ig, float* __restrict__ gi)
{
  int b = blockIdx.x; int tid = threadIdx.x;
  int n = blockIdx.y * 256 + tid;
  __shared__ float gp[512];
  #pragma unroll
  for (int r = 0; r < 2; ++r) {
    int e = r * 256 + tid;
    float a = 0.f;
    #pragma unroll
    for (int ch = 0; ch < 8; ++ch) a += gpart[(size_t)(b * 8 + ch) * 512 + e];
    gp[e] = a * (1.f / 1024.f);
  }
  __syncthreads();
  float a = b_ig[n];
  for (int e4 = 0; e4 < 128; ++e4) {
    float4 g4 = *(const float4*)&gp[e4 * 4];
    const float* w = W_ig + (size_t)e4 * 4 * 1024 + n;
    a += g4.x * w[0] + g4.y * w[1024] + g4.z * w[2048] + g4.w * w[3072];
  }
  gi[b * 1024 + n] = a;
}

// ---------------- gm[b,s,n] = tanh(memory[b,s]) @ W_mg[s] + b_mg[s] ----------------
__global__ __launch_bounds__(256) void k_gm_kernel(
    const float* __restrict__ tm, const float* __restrict__ W_mg,
    const float* __restrict__ b_mg, float* __restrict__ gm)
{
  int s = blockIdx.x;
  int n = blockIdx.y * 256 + threadIdx.x;
  int b0 = blockIdx.z * 8;
  float acc[8];
  #pragma unroll
  for (int i = 0; i < 8; ++i) acc[i] = 0.f;
  const float* wp = W_mg + (size_t)s * 512 * 1024 + n;
  for (int e4 = 0; e4 < 128; ++e4) {
    float w0 = wp[(size_t)(e4 * 4 + 0) * 1024];
    float w1 = wp[(size_t)(e4 * 4 + 1) * 1024];
    float w2 = wp[(size_t)(e4 * 4 + 2) * 1024];
    float w3 = wp[(size_t)(e4 * 4 + 3) * 1024];
    #pragma unroll
    for (int i = 0; i < 8; ++i) {
      const float4 t4 = *(const float4*)(tm + ((size_t)((b0 + i) * 8 + s)) * 512 + e4 * 4);
      acc[i] += t4.x * w0 + t4.y * w1 + t4.z * w2 + t4.w * w3;
    }
  }
  float bm = b_mg[s * 1024 + n];
  #pragma unroll
  for (int i = 0; i < 8; ++i)
    gm[((size_t)((b0 + i) * 8 + s)) * 1024 + n] = acc[i] + bm;
}

// ---------------- gating ----------------
__global__ void k_gate_kernel(const float* __restrict__ gi, const float* __restrict__ gm,
                              const float* __restrict__ nm_ln, const float* __restrict__ memory,
                              const float* __restrict__ fbias, const float* __restrict__ ibias,
                              float* __restrict__ nmem)
{
  int idx = blockIdx.x * 256 + threadIdx.x;   // 131072
  int b = idx >> 12; int rem = idx & 4095; int s = rem >> 9; int e = rem & 511;
  float fb = fbias[0], ib = ibias[0];
  size_t gidx = (size_t)(b * 8 + s) * 1024;
  float ing = 1.f / (1.f + __expf(-(gi[b * 1024 + e] + gm[gidx + e] + ib)));
  float fg  = 1.f / (1.f + __expf(-(gi[b * 1024 + 512 + e] + gm[gidx + 512 + e] + fb)));
  nmem[idx] = ing * tanhf(nm_ln[idx]) + fg * memory[idx];
}

// ---------------- k_mem / v_mem from new memory ----------------
__global__ __launch_bounds__(256) void k_kvmem_kernel(
    const float* __restrict__ nmem, const float* __restrict__ Wk, const float* __restrict__ bk,
    const float* __restrict__ Wv, const float* __restrict__ bv,
    float* __restrict__ k_mem, float* __restrict__ v_mem)
{
  int b = blockIdx.x, chunk = blockIdx.y;   // 10 chunks
  int tid = threadIdx.x;
  __shared__ float nm[4096];
  for (int i = tid; i < 1024; i += 256)
    *(float4*)&nm[i * 4] = *(const float4*)&nmem[(size_t)b * 4096 + i * 4];
  __syncthreads();
  if (chunk < 2) {
    for (int r = 0; r < 2; ++r) {
      int o = chunk * 512 + r * 256 + tid;   // 0..1023
      int s = o >> 7, j = o & 127;
      float a = bk[j];
      for (int e4 = 0; e4 < 128; ++e4) {
        float4 m4 = *(const float4*)&nm[s * 512 + e4 * 4];
        const float* w = Wk + (size_t)e4 * 4 * 128 + j;
        a += m4.x * w[0] + m4.y * w[128] + m4.z * w[256] + m4.w * w[384];
      }
      k_mem[(size_t)b * 1024 + o] = a;
    }
  } else {
    int cv = chunk - 2;                      // slot
    for (int r = 0; r < 2; ++r) {
      int c = r * 256 + tid;
      float a = bv[c];
      for (int e4 = 0; e4 < 128; ++e4) {
        float4 m4 = *(const float4*)&nm[cv * 512 + e4 * 4];
        const float* w = Wv + (size_t)e4 * 4 * 512 + c;
        a += m4.x * w[0] + m4.y * w[512] + m4.z * w[1024] + m4.w * w[1536];
      }
      v_mem[((size_t)b * 8 + cv) * 512 + c] = a;
    }
  }
}

// ---------------- final broadcast attention -> out (T,B,E) ----------------
__global__ __launch_bounds__(256) void k_out_attn(
    const u16* __restrict__ kq, const float* __restrict__ k_mem,
    const float* __restrict__ v_mem, float* __restrict__ out)
{
  int b = blockIdx.x, tc = blockIdx.y;
  int tid = threadIdx.x;
  __shared__ float km[1024];
  __shared__ float vm[4096];
  __shared__ float pr[4096];   // [tt][h][s]
  for (int i = tid; i < 1024; i += 256) km[i] = k_mem[(size_t)b * 1024 + i];
  for (int i = tid; i < 4096; i += 256) vm[i] = v_mem[(size_t)b * 4096 + i];
  __syncthreads();
  #pragma unroll
  for (int pi = 0; pi < 2; ++pi) {
    int p = pi * 256 + tid;
    int tt = p >> 3, hh = p & 7;
    int t = tc * 64 + tt;
    const u16* qrow = kq + ((size_t)(b * 1024 + t)) * 256 + 128 + hh * 16;
    float q[16];
    #pragma unroll
    for (int d = 0; d < 16; ++d) q[d] = b2f(qrow[d]);
    float s8[8]; float mx = -1e38f;
    #pragma unroll
    for (int s = 0; s < 8; ++s) {
      float a = 0.f;
      #pragma unroll
      for (int d = 0; d < 16; ++d) a += q[d] * km[s * 128 + hh * 16 + d];
      s8[s] = a; mx = fmaxf(mx, a);
    }
    float se = 0.f;
    #pragma unroll
    for (int s = 0; s < 8; ++s) { s8[s] = __expf(s8[s] - mx); se += s8[s]; }
    float inv = 1.f / se;
    #pragma unroll
    for (int s = 0; s < 8; ++s) pr[(tt * 8 + hh) * 8 + s] = s8[s] * inv;
  }
  __syncthreads();
  for (int oi = 0; oi < 128; ++oi) {
    int o = oi * 256 + tid;
    int tt = o >> 9, c = o & 511, hh = c >> 6;
    float a = 0.f;
    #pragma unroll
    for (int s = 0; s < 8; ++s) a += pr[(tt * 8 + hh) * 8 + s] * vm[s * 512 + c];
    int t = tc * 64 + tt;
    out[((size_t)t * 32 + b) * 512 + c] = a;
  }
}

extern "C" void kernel_launch(void* const* d_in, const int* in_sizes, int n_in,
                              void* d_out, int out_size, void* d_ws, size_t ws_size,
                              hipStream_t stream) {
  (void)in_sizes; (void)n_in; (void)out_size; (void)ws_size;
  const float* key   = (const float*)d_in[1];
  const float* memory= (const float*)d_in[2];
  const float* W_in  = (const float*)d_in[3];
  const float* b_in  = (const float*)d_in[4];
  const float* Wq    = (const float*)d_in[5];
  const float* bq    = (const float*)d_in[6];
  const float* Wk    = (const float*)d_in[7];
  const float* bk    = (const float*)d_in[8];
  const float* Wv    = (const float*)d_in[9];
  const float* bv    = (const float*)d_in[10];
  const float* W_mlp = (const float*)d_in[11];
  const float* b_mlp = (const float*)d_in[12];
  const float* g1    = (const float*)d_in[13];
  const float* be1   = (const float*)d_in[14];
  const float* g2    = (const float*)d_in[15];
  const float* be2   = (const float*)d_in[16];
  const float* w_rep = (const float*)d_in[17];
  const float* W_ig  = (const float*)d_in[18];
  const float* b_ig  = (const float*)d_in[19];
  const float* W_mg  = (const float*)d_in[20];
  const float* b_mg  = (const float*)d_in[21];
  const float* fbias = (const float*)d_in[22];
  const float* ibias = (const float*)d_in[23];
  float* out = (float*)d_out;

  char* p = (char*)d_ws;
  auto alloc = [&](size_t bytes) { char* r = p; p += (bytes + 255) & ~(size_t)255; return r; };
  u16* x       = (u16*)alloc(33554432);    // x bf16 (B,T,E)
  u16* kq      = (u16*)alloc(16777216);    // [k | q] bf16 (B*T, 256)
  u16* WinT    = (u16*)alloc(524288);
  u16* WkqT    = (u16*)alloc(262144);
  float* bkq   = (float*)alloc(1024);
  float* gpart = (float*)alloc(524288);    // (B, 8, 512)
  float* gi    = (float*)alloc(131072);
  float* gm    = (float*)alloc(1048576);
  float* att   = (float*)alloc(524288);
  float* nm_ln = (float*)alloc(524288);
  float* nmem  = (float*)alloc(524288);
  float* kmem  = (float*)alloc(131072);
  float* vmem  = (float*)alloc(524288);
  float* tm    = (float*)alloc(524288);
  float* qmw   = (float*)alloc(131072);    // (B, 8, 128)
  float* p3    = (float*)alloc(32768);     // (B, H, S, 4)
  int*   idx3  = (int*)alloc(24576);       // (B, H, S, 3)

  k_conv_win<<<1024, 256, 0, stream>>>(W_in, WinT);
  k_conv_wkq<<<512, 256, 0, stream>>>(Wk, Wq, bk, bq, WkqT, bkq);
  k_tanh_mem<<<512, 256, 0, stream>>>(memory, tm);
  gemm_kernel<1><<<dim3(256, 4), 256, 0, stream>>>(key, WinT, b_in, x, 32768, 512, 512);
  gemm_kernel<0><<<dim3(256, 2), 256, 0, stream>>>(x, WkqT, bkq, kq, 32768, 256, 512);
  k_qm<<<dim3(32, 8), 256, 0, stream>>>(memory, Wq, bq, qmw);
  k_scores_topk<<<dim3(32, 8, 8), 256, 0, stream>>>(qmw, kq, p3, idx3);
  k_attval<<<dim3(32, 8), 512, 0, stream>>>(x, p3, idx3, Wv, bv, att);
  k_gipre<<<dim3(32, 8), 256, 0, stream>>>(x, w_rep, gpart);
  k_mem_lnmlp<<<dim3(32, 8), 256, 0, stream>>>(memory, att, g1, be1, W_mlp, b_mlp, g2, be2, nm_ln);
  k_gi_kernel<<<dim3(32, 4), 256, 0, stream>>>(gpart, W_ig, b_ig, gi);
  k_gm_kernel<<<dim3(8, 4, 4), 256, 0, stream>>>(tm, W_mg, b_mg, gm);
  k_gate_kernel<<<512, 256, 0, stream>>>(gi, gm, nm_ln, memory, fbias, ibias, nmem);
  k_kvmem_kernel<<<dim3(32, 10), 256, 0, stream>>>(nmem, Wk, bk, Wv, bv, kmem, vmem);
  k_out_attn<<<dim3(32, 16), 256, 0, stream>>>(kq, kmem, vmem, out);
}

// Round 3
// 263.321 us; speedup vs baseline: 1.6194x; 1.1117x over previous
//
#include <hip/hip_runtime.h>
#include <stdint.h>

typedef unsigned short u16;
typedef __bf16 bf16x8 __attribute__((ext_vector_type(8)));
typedef float f32x4 __attribute__((ext_vector_type(4)));

// Problem constants: T=1024, B=32, E=512, HEADS=8, KEYD=16, HEAD=64, MEM_SLOTS=8, TOPK=3

__device__ __forceinline__ u16 f2b(float f) {
  union { float f; uint32_t u; } v; v.f = f;
  return (u16)((v.u + 0x7FFFu + ((v.u >> 16) & 1u)) >> 16);
}
__device__ __forceinline__ float b2f(u16 h) {
  union { uint32_t u; float f; } v; v.u = ((uint32_t)h) << 16; return v.f;
}
__device__ __forceinline__ void gload_lds16(const void* g, void* l) {
  __builtin_amdgcn_global_load_lds(
      (const __attribute__((address_space(1))) unsigned int*)g,
      (__attribute__((address_space(3))) unsigned int*)l, 16, 0, 0);
}

// ---------------- fused prep: WinT, WkqT+bkq, WvT, tanh(memory) ----------------
__global__ void k_prep(const float* __restrict__ W_in, u16* __restrict__ WinT,
                       const float* __restrict__ Wk, const float* __restrict__ Wq,
                       const float* __restrict__ bk, const float* __restrict__ bq,
                       u16* __restrict__ WkqT, float* __restrict__ bkq,
                       const float* __restrict__ Wv, u16* __restrict__ WvT,
                       const float* __restrict__ mem, float* __restrict__ tm) {
  int idx = blockIdx.x * 256 + threadIdx.x;   // 786432 total
  if (idx < 262144) {
    int k = idx >> 9, n = idx & 511;
    WinT[n * 512 + k] = f2b(W_in[idx]);
  } else if (idx < 393216) {
    int j = idx - 262144;
    if (j < 65536) {
      int k = j >> 7, n = j & 127;
      WkqT[n * 512 + k] = f2b(Wk[j]);
    } else {
      int jj = j - 65536;
      int k = jj >> 7, n = jj & 127;
      WkqT[(128 + n) * 512 + k] = f2b(Wq[jj]);
    }
    if (j < 128) bkq[j] = bk[j];
    else if (j < 256) bkq[j] = bq[j - 128];
  } else if (idx < 655360) {
    int j = idx - 393216;
    int k = j >> 9, n = j & 511;
    WvT[n * 512 + k] = f2b(Wv[j]);
  } else {
    int j = idx - 655360;
    tm[j] = tanhf(mem[j]);
  }
}

// ---------------- bf16 MFMA GEMM: C[M,N] = A[M,K] @ Bt[N,K]^T + bias ----------------
// AMODE 0: A bf16 row-major, staged via global_load_lds. AMODE 1: A f32 'key' (T,B,E), reg-convert.
template<int AMODE>
__global__ __launch_bounds__(256) void gemm_kernel(
    const void* __restrict__ Ap, const u16* __restrict__ Bt,
    const float* __restrict__ bias, u16* __restrict__ C,
    const int M, const int N, const int K)
{
  __shared__ u16 As[128 * 32];
  __shared__ u16 Bs[128 * 32];
  const int tid = threadIdx.x;
  const int m0 = blockIdx.x * 128;
  const int n0 = blockIdx.y * 128;
  const int lane = tid & 63;
  const int wid = tid >> 6;
  const int wm = (wid >> 1) * 64;
  const int wn = (wid & 1) * 64;

  f32x4 acc[4][4];
  #pragma unroll
  for (int i = 0; i < 4; ++i)
    #pragma unroll
    for (int j = 0; j < 4; ++j) acc[i][j] = (f32x4){0.f, 0.f, 0.f, 0.f};

  const int nk = K >> 5;
  for (int kt = 0; kt < nk; ++kt) {
    const int k0 = kt << 5;
    __syncthreads();
    if (AMODE == 0) {
      const u16* A = (const u16*)Ap;
      #pragma unroll
      for (int c = 0; c < 2; ++c) {
        int o = c * 2048 + tid * 8;
        int row = o >> 5, ck = o & 31;
        gload_lds16(A + (size_t)(m0 + row) * K + k0 + ck, As + o);
      }
    } else {
      #pragma unroll
      for (int cc = 0; cc < 2; ++cc) {
        const int chunk = tid * 2 + cc;       // 0..511
        const int row = chunk >> 2;           // 0..127
        const int off = (chunk & 3) * 8;      // 0,8,16,24
        const float* A = (const float*)Ap;
        const int r = m0 + row;
        const int bb = r >> 10, t = r & 1023;
        const float* src = A + ((size_t)t * 32 + bb) * 512 + k0 + off;
        float4 lo = *(const float4*)src;
        float4 hi = *(const float4*)(src + 4);
        uint4 o4;
        o4.x = (uint32_t)f2b(lo.x) | ((uint32_t)f2b(lo.y) << 16);
        o4.y = (uint32_t)f2b(lo.z) | ((uint32_t)f2b(lo.w) << 16);
        o4.z = (uint32_t)f2b(hi.x) | ((uint32_t)f2b(hi.y) << 16);
        o4.w = (uint32_t)f2b(hi.z) | ((uint32_t)f2b(hi.w) << 16);
        *(uint4*)(As + row * 32 + off) = o4;
      }
    }
    #pragma unroll
    for (int c = 0; c < 2; ++c) {
      int o = c * 2048 + tid * 8;
      int row = o >> 5, ck = o & 31;
      gload_lds16(Bt + (size_t)(n0 + row) * K + k0 + ck, Bs + o);
    }
    __syncthreads();
    const int r = lane & 15;
    const int kb = (lane >> 4) * 8;
    bf16x8 af[4], bfr[4];
    #pragma unroll
    for (int i = 0; i < 4; ++i) {
      af[i]  = *(const bf16x8*)(As + (wm + i * 16 + r) * 32 + kb);
      bfr[i] = *(const bf16x8*)(Bs + (wn + i * 16 + r) * 32 + kb);
    }
    #pragma unroll
    for (int i = 0; i < 4; ++i)
      #pragma unroll
      for (int j = 0; j < 4; ++j)
        acc[i][j] = __builtin_amdgcn_mfma_f32_16x16x32_bf16(af[i], bfr[j], acc[i][j], 0, 0, 0);
  }
  const int cl = lane & 15;
  const int rl = (lane >> 4) * 4;
  #pragma unroll
  for (int j = 0; j < 4; ++j) {
    const int col = n0 + wn + j * 16 + cl;
    const float bsv = bias[col];
    #pragma unroll
    for (int i = 0; i < 4; ++i) {
      #pragma unroll
      for (int rr = 0; rr < 4; ++rr) {
        const int row = m0 + wm + i * 16 + rl + rr;
        C[(size_t)row * N + col] = f2b(acc[i][j][rr] + bsv);
      }
    }
  }
}

// ---------------- qm[b,s,h*16+d] = memory[b,s,:] @ Wq + bq ----------------
__global__ __launch_bounds__(256) void k_qm(
    const float* __restrict__ memory, const float* __restrict__ Wq,
    const float* __restrict__ bq, float* __restrict__ qm)
{
  const int b = blockIdx.x, s = blockIdx.y;
  const int tid = threadIdx.x;
  const int col = tid & 127, half = tid >> 7;
  __shared__ float mrow[512];
  __shared__ float part[2][128];
  *(float2*)&mrow[tid * 2] = *(const float2*)&memory[(size_t)(b * 8 + s) * 512 + tid * 2];
  __syncthreads();
  float a = 0.f;
  const int e0 = half * 256;
  for (int e = 0; e < 256; ++e)
    a += mrow[e0 + e] * Wq[(size_t)(e0 + e) * 128 + col];
  part[half][col] = a;
  __syncthreads();
  if (tid < 128)
    qm[(size_t)(b * 8 + s) * 128 + tid] = part[0][tid] + part[1][tid] + bq[tid];
}

// ---------------- scores + top3 + softmax per (b,h,s) ----------------
__global__ __launch_bounds__(256) void k_scores_topk(
    const float* __restrict__ qm, const u16* __restrict__ kq,
    float* __restrict__ p3, int* __restrict__ idx3)
{
  const int b = blockIdx.x, h = blockIdx.y, s = blockIdx.z;
  const int tid = threadIdx.x;
  __shared__ float swv[4];
  __shared__ int   swi[4];
  __shared__ float ssv[4];

  float q[16];
  const float* qp = qm + ((size_t)(b * 8 + s) * 128 + h * 16);
  #pragma unroll
  for (int d = 0; d < 16; ++d) q[d] = qp[d];

  float sc[4];
  #pragma unroll
  for (int j = 0; j < 4; ++j) {
    const int t = j * 256 + tid;
    const u16* kr = kq + ((size_t)(b * 1024 + t)) * 256 + h * 16;
    uint4 v0 = *(const uint4*)kr;
    uint4 v1 = *(const uint4*)(kr + 8);
    const u16* p0 = (const u16*)&v0;
    const u16* p1 = (const u16*)&v1;
    float a = 0.f;
    #pragma unroll
    for (int d = 0; d < 8; ++d) a += q[d] * b2f(p0[d]);
    #pragma unroll
    for (int d = 0; d < 8; ++d) a += q[8 + d] * b2f(p1[d]);
    sc[j] = a;
  }

  int   seli[3];
  float selv[3];
  float ssum = 0.f;
  #pragma unroll
  for (int pass = 0; pass < 3; ++pass) {
    float bv_ = -1e30f; int bi_ = 1 << 30;
    #pragma unroll
    for (int j = 0; j < 4; ++j) {
      const int t = j * 256 + tid;
      bool skip = false;
      for (int k = 0; k < pass; ++k) skip |= (t == seli[k]);
      float v = skip ? -1e30f : sc[j];
      if (v > bv_ || (v == bv_ && t < bi_)) { bv_ = v; bi_ = t; }
    }
    #pragma unroll
    for (int o = 32; o > 0; o >>= 1) {
      float ov = __shfl_xor(bv_, o);
      int   oi = __shfl_xor(bi_, o);
      if (ov > bv_ || (ov == bv_ && oi < bi_)) { bv_ = ov; bi_ = oi; }
    }
    __syncthreads();
    if ((tid & 63) == 0) { swv[tid >> 6] = bv_; swi[tid >> 6] = bi_; }
    __syncthreads();
    float wv = swv[0]; int wi = swi[0];
    #pragma unroll
    for (int w = 1; w < 4; ++w) {
      float ov = swv[w]; int oi = swi[w];
      if (ov > wv || (ov == wv && oi < wi)) { wv = ov; wi = oi; }
    }
    selv[pass] = wv; seli[pass] = wi;

    if (pass == 0) {
      float se = 0.f;
      #pragma unroll
      for (int j = 0; j < 4; ++j) se += __expf(sc[j] - wv);
      #pragma unroll
      for (int o = 32; o > 0; o >>= 1) se += __shfl_xor(se, o);
      __syncthreads();
      if ((tid & 63) == 0) ssv[tid >> 6] = se;
      __syncthreads();
      ssum = ssv[0] + ssv[1] + ssv[2] + ssv[3];
    }
  }

  if (tid == 0) {
    const float m0 = selv[0];
    const float inv = 1.f / ssum;
    const size_t base = (size_t)(b * 64 + h * 8 + s);
    float sp = 0.f;
    #pragma unroll
    for (int j = 0; j < 3; ++j) {
      float pj = __expf(selv[j] - m0) * inv;
      p3[base * 4 + j] = pj;
      idx3[base * 3 + j] = seli[j];
      sp += pj;
    }
    p3[base * 4 + 3] = sp;
  }
}

// ---------------- XW[h][b*8+s][e] = sum_j p_j * x[b, i_j][e]  (bf16) ----------------
__global__ __launch_bounds__(256) void k_xw(
    const u16* __restrict__ x, const float* __restrict__ p3, const int* __restrict__ idx3,
    u16* __restrict__ XW)
{
  const int b = blockIdx.x, s = blockIdx.y;
  const int tid = threadIdx.x;
  const int h = tid >> 5, l = tid & 31;
  const size_t base = (size_t)(b * 64 + h * 8 + s);
  const float p0 = p3[base * 4 + 0];
  const float p1 = p3[base * 4 + 1];
  const float p2 = p3[base * 4 + 2];
  const int i0 = idx3[base * 3 + 0];
  const int i1 = idx3[base * 3 + 1];
  const int i2 = idx3[base * 3 + 2];
  const u16* xb = x + ((size_t)b << 19) + l * 16;
  uint4 a0 = *(const uint4*)(xb + ((size_t)i0 << 9));
  uint4 a0h = *(const uint4*)(xb + ((size_t)i0 << 9) + 8);
  uint4 a1 = *(const uint4*)(xb + ((size_t)i1 << 9));
  uint4 a1h = *(const uint4*)(xb + ((size_t)i1 << 9) + 8);
  uint4 a2 = *(const uint4*)(xb + ((size_t)i2 << 9));
  uint4 a2h = *(const uint4*)(xb + ((size_t)i2 << 9) + 8);
  const u16* e0 = (const u16*)&a0; const u16* e0h = (const u16*)&a0h;
  const u16* e1 = (const u16*)&a1; const u16* e1h = (const u16*)&a1h;
  const u16* e2 = (const u16*)&a2; const u16* e2h = (const u16*)&a2h;
  u16 ov[16];
  #pragma unroll
  for (int k = 0; k < 8; ++k)
    ov[k] = f2b(p0 * b2f(e0[k]) + p1 * b2f(e1[k]) + p2 * b2f(e2[k]));
  #pragma unroll
  for (int k = 0; k < 8; ++k)
    ov[8 + k] = f2b(p0 * b2f(e0h[k]) + p1 * b2f(e1h[k]) + p2 * b2f(e2h[k]));
  u16* dst = XW + (size_t)h * 131072 + (size_t)(b * 8 + s) * 512 + l * 16;
  *(uint4*)dst = *(const uint4*)&ov[0];
  *(uint4*)(dst + 8) = *(const uint4*)&ov[8];
}

// ---------------- att via per-head MFMA GEMM: att[row, h*64+c] = XW_h[row,:] @ WvT_h + sp*bv ----------------
__global__ __launch_bounds__(256) void k_attgemm(
    const u16* __restrict__ XW, const u16* __restrict__ WvT,
    const float* __restrict__ p3, const float* __restrict__ bvv,
    float* __restrict__ att)
{
  __shared__ u16 As[128 * 32];
  __shared__ u16 Bs[64 * 32];
  const int h = blockIdx.x;
  const int m0 = blockIdx.y * 128;
  const int tid = threadIdx.x;
  const int lane = tid & 63;
  const int wid = tid >> 6;
  const int wm = wid * 32;
  const u16* A = XW + (size_t)h * 131072;
  const u16* Bh = WvT + (size_t)h * 64 * 512;

  f32x4 acc[2][4];
  #pragma unroll
  for (int i = 0; i < 2; ++i)
    #pragma unroll
    for (int j = 0; j < 4; ++j) acc[i][j] = (f32x4){0.f, 0.f, 0.f, 0.f};

  for (int kt = 0; kt < 16; ++kt) {
    const int k0 = kt << 5;
    __syncthreads();
    #pragma unroll
    for (int c = 0; c < 2; ++c) {
      int o = c * 2048 + tid * 8;
      int row = o >> 5, ck = o & 31;
      gload_lds16(A + (size_t)(m0 + row) * 512 + k0 + ck, As + o);
    }
    {
      int row = tid >> 2, ck = (tid & 3) * 8;
      gload_lds16(Bh + (size_t)row * 512 + k0 + ck, Bs + row * 32 + ck);
    }
    __syncthreads();
    const int r = lane & 15;
    const int kb = (lane >> 4) * 8;
    bf16x8 af[2], bfr[4];
    #pragma unroll
    for (int i = 0; i < 2; ++i)
      af[i] = *(const bf16x8*)(As + (wm + i * 16 + r) * 32 + kb);
    #pragma unroll
    for (int j = 0; j < 4; ++j)
      bfr[j] = *(const bf16x8*)(Bs + (j * 16 + r) * 32 + kb);
    #pragma unroll
    for (int i = 0; i < 2; ++i)
      #pragma unroll
      for (int j = 0; j < 4; ++j)
        acc[i][j] = __builtin_amdgcn_mfma_f32_16x16x32_bf16(af[i], bfr[j], acc[i][j], 0, 0, 0);
  }
  const int cl = lane & 15;
  const int rl = (lane >> 4) * 4;
  #pragma unroll
  for (int i = 0; i < 2; ++i) {
    #pragma unroll
    for (int rr = 0; rr < 4; ++rr) {
      const int row = m0 + wm + i * 16 + rl + rr;   // = b*8+s
      const int bb = row >> 3, ss = row & 7;
      const float sp = p3[(size_t)(bb * 64 + h * 8 + ss) * 4 + 3];
      #pragma unroll
      for (int j = 0; j < 4; ++j) {
        const int col = h * 64 + j * 16 + cl;
        att[(size_t)row * 512 + col] = acc[i][j][rr] + sp * bvv[col];
      }
    }
  }
}

// ---------------- gi partials: gpart[b,ch,e] = sum over 128 tokens of relu(w_rep*x) ----------------
__global__ __launch_bounds__(256) void k_gipre(
    const u16* __restrict__ x, const float* __restrict__ w_rep,
    float* __restrict__ gpart)
{
  const int b = blockIdx.x, ch = blockIdx.y;
  const int tid = threadIdx.x;
  const int e8 = tid & 63, tp = tid >> 6;
  float w[8], acc[8];
  #pragma unroll
  for (int k = 0; k < 8; ++k) { w[k] = w_rep[e8 * 8 + k]; acc[k] = 0.f; }
  const int t0 = ch * 128 + tp * 32;
  for (int tt = 0; tt < 32; ++tt) {
    uint4 v = *(const uint4*)(x + ((size_t)(b * 1024 + t0 + tt) << 9) + e8 * 8);
    const u16* pv = (const u16*)&v;
    #pragma unroll
    for (int k = 0; k < 8; ++k) acc[k] += fmaxf(w[k] * b2f(pv[k]), 0.f);
  }
  __shared__ float ps[4][512];
  #pragma unroll
  for (int k = 0; k < 8; ++k) ps[tp][e8 * 8 + k] = acc[k];
  __syncthreads();
  #pragma unroll
  for (int r = 0; r < 2; ++r) {
    int e = r * 256 + tid;
    gpart[(size_t)(b * 8 + ch) * 512 + e] = ps[0][e] + ps[1][e] + ps[2][e] + ps[3][e];
  }
}

// ---------------- LN1 + MLP + LN2 per (b,slot) ----------------
__global__ __launch_bounds__(256) void k_mem_lnmlp(
    const float* __restrict__ memory, const float* __restrict__ att,
    const float* __restrict__ g1, const float* __restrict__ be1,
    const float* __restrict__ W_mlp, const float* __restrict__ b_mlp,
    const float* __restrict__ g2, const float* __restrict__ be2,
    float* __restrict__ nm_ln)
{
  const int b = blockIdx.x, s = blockIdx.y;
  const int tid = threadIdx.x;
  __shared__ float m_s[512];
  __shared__ float r1[256], r2[256];
  const size_t base = (size_t)(b * 8 + s) * 512;
  float v0 = memory[base + tid] + att[base + tid];
  float v1 = memory[base + 256 + tid] + att[base + 256 + tid];
  r1[tid] = v0 + v1; r2[tid] = v0 * v0 + v1 * v1;
  __syncthreads();
  for (int off = 128; off > 0; off >>= 1) {
    if (tid < off) { r1[tid] += r1[tid + off]; r2[tid] += r2[tid + off]; }
    __syncthreads();
  }
  float mu = r1[0] * (1.f / 512.f);
  float var = r2[0] * (1.f / 512.f) - mu * mu;
  float rs = rsqrtf(var + 1e-5f);
  __syncthreads();
  m_s[tid]       = (v0 - mu) * rs * g1[tid] + be1[tid];
  m_s[tid + 256] = (v1 - mu) * rs * g1[tid + 256] + be1[tid + 256];
  __syncthreads();
  float d0 = b_mlp[tid], d1 = b_mlp[tid + 256];
  for (int c4 = 0; c4 < 128; ++c4) {
    float4 m4 = *(const float4*)&m_s[c4 * 4];
    const float* w = W_mlp + (size_t)c4 * 4 * 512;
    d0 += m4.x * w[tid];        d1 += m4.x * w[tid + 256];
    d0 += m4.y * w[512 + tid];  d1 += m4.y * w[512 + tid + 256];
    d0 += m4.z * w[1024 + tid]; d1 += m4.z * w[1024 + tid + 256];
    d0 += m4.w * w[1536 + tid]; d1 += m4.w * w[1536 + tid + 256];
  }
  float h0 = m_s[tid] + fmaxf(d0, 0.f);
  float h1 = m_s[tid + 256] + fmaxf(d1, 0.f);
  __syncthreads();
  r1[tid] = h0 + h1; r2[tid] = h0 * h0 + h1 * h1;
  __syncthreads();
  for (int off = 128; off > 0; off >>= 1) {
    if (tid < off) { r1[tid] += r1[tid + off]; r2[tid] += r2[tid + off]; }
    __syncthreads();
  }
  float mu2 = r1[0] * (1.f / 512.f);
  float var2 = r2[0] * (1.f / 512.f) - mu2 * mu2;
  float rs2 = rsqrtf(var2 + 1e-5f);
  nm_ln[base + tid]       = (h0 - mu2) * rs2 * g2[tid] + be2[tid];
  nm_ln[base + 256 + tid] = (h1 - mu2) * rs2 * g2[tid + 256] + be2[tid + 256];
}

// ---------------- gi = (sum gpart / 1024) @ W_ig + b_ig ----------------
__global__ void k_gi_kernel(const float* __restrict__ gpart, const float* __restrict__ W_ig,
                            const float* __restrict__ b_ig, float* __restrict__ gi)
{
  int b = blockIdx.x; int tid = threadIdx.x;
  int n = blockIdx.y * 256 + tid;
  __shared__ float gp[512];
  #pragma unroll
  for (int r = 0; r < 2; ++r) {
    int e = r * 256 + tid;
    float a = 0.f;
    #pragma unroll
    for (int ch = 0; ch < 8; ++ch) a += gpart[(size_t)(b * 8 + ch) * 512 + e];
    gp[e] = a * (1.f / 1024.f);
  }
  __syncthreads();
  float a = b_ig[n];
  for (int e4 = 0; e4 < 128; ++e4) {
    float4 g4 = *(const float4*)&gp[e4 * 4];
    const float* w = W_ig + (size_t)e4 * 4 * 1024 + n;
    a += g4.x * w[0] + g4.y * w[1024] + g4.z * w[2048] + g4.w * w[3072];
  }
  gi[b * 1024 + n] = a;
}

// ---------------- gm[b,s,n] = tanh(memory[b,s]) @ W_mg[s] + b_mg[s] ----------------
__global__ __launch_bounds__(256) void k_gm_kernel(
    const float* __restrict__ tm, const float* __restrict__ W_mg,
    const float* __restrict__ b_mg, float* __restrict__ gm)
{
  int s = blockIdx.x;
  int n = blockIdx.y * 256 + threadIdx.x;
  int b0 = blockIdx.z * 8;
  float acc[8];
  #pragma unroll
  for (int i = 0; i < 8; ++i) acc[i] = 0.f;
  const float* wp = W_mg + (size_t)s * 512 * 1024 + n;
  for (int e4 = 0; e4 < 128; ++e4) {
    float w0 = wp[(size_t)(e4 * 4 + 0) * 1024];
    float w1 = wp[(size_t)(e4 * 4 + 1) * 1024];
    float w2 = wp[(size_t)(e4 * 4 + 2) * 1024];
    float w3 = wp[(size_t)(e4 * 4 + 3) * 1024];
    #pragma unroll
    for (int i = 0; i < 8; ++i) {
      const float4 t4 = *(const float4*)(tm + ((size_t)((b0 + i) * 8 + s)) * 512 + e4 * 4);
      acc[i] += t4.x * w0 + t4.y * w1 + t4.z * w2 + t4.w * w3;
    }
  }
  float bm = b_mg[s * 1024 + n];
  #pragma unroll
  for (int i = 0; i < 8; ++i)
    gm[((size_t)((b0 + i) * 8 + s)) * 1024 + n] = acc[i] + bm;
}

// ---------------- gating ----------------
__global__ void k_gate_kernel(const float* __restrict__ gi, const float* __restrict__ gm,
                              const float* __restrict__ nm_ln, const float* __restrict__ memory,
                              const float* __restrict__ fbias, const float* __restrict__ ibias,
                              float* __restrict__ nmem)
{
  int idx = blockIdx.x * 256 + threadIdx.x;   // 131072
  int b = idx >> 12; int rem = idx & 4095; int s = rem >> 9; int e = rem & 511;
  float fb = fbias[0], ib = ibias[0];
  size_t gidx = (size_t)(b * 8 + s) * 1024;
  float ing = 1.f / (1.f + __expf(-(gi[b * 1024 + e] + gm[gidx + e] + ib)));
  float fg  = 1.f / (1.f + __expf(-(gi[b * 1024 + 512 + e] + gm[gidx + 512 + e] + fb)));
  nmem[idx] = ing * tanhf(nm_ln[idx]) + fg * memory[idx];
}

// ---------------- k_mem / v_mem from new memory ----------------
__global__ __launch_bounds__(256) void k_kvmem_kernel(
    const float* __restrict__ nmem, const float* __restrict__ Wk, const float* __restrict__ bk,
    const float* __restrict__ Wv, const float* __restrict__ bv,
    float* __restrict__ k_mem, float* __restrict__ v_mem)
{
  int b = blockIdx.x, chunk = blockIdx.y;   // 10 chunks
  int tid = threadIdx.x;
  __shared__ float nm[4096];
  for (int i = tid; i < 1024; i += 256)
    *(float4*)&nm[i * 4] = *(const float4*)&nmem[(size_t)b * 4096 + i * 4];
  __syncthreads();
  if (chunk < 2) {
    for (int r = 0; r < 2; ++r) {
      int o = chunk * 512 + r * 256 + tid;   // 0..1023
      int s = o >> 7, j = o & 127;
      float a = bk[j];
      for (int e4 = 0; e4 < 128; ++e4) {
        float4 m4 = *(const float4*)&nm[s * 512 + e4 * 4];
        const float* w = Wk + (size_t)e4 * 4 * 128 + j;
        a += m4.x * w[0] + m4.y * w[128] + m4.z * w[256] + m4.w * w[384];
      }
      k_mem[(size_t)b * 1024 + o] = a;
    }
  } else {
    int cv = chunk - 2;                      // slot
    for (int r = 0; r < 2; ++r) {
      int c = r * 256 + tid;
      float a = bv[c];
      for (int e4 = 0; e4 < 128; ++e4) {
        float4 m4 = *(const float4*)&nm[cv * 512 + e4 * 4];
        const float* w = Wv + (size_t)e4 * 4 * 512 + c;
        a += m4.x * w[0] + m4.y * w[512] + m4.z * w[1024] + m4.w * w[1536];
      }
      v_mem[((size_t)b * 8 + cv) * 512 + c] = a;
    }
  }
}

// ---------------- final broadcast attention -> out (T,B,E) ----------------
__global__ __launch_bounds__(256) void k_out_attn(
    const u16* __restrict__ kq, const float* __restrict__ k_mem,
    const float* __restrict__ v_mem, float* __restrict__ out)
{
  int b = blockIdx.x, tc = blockIdx.y;
  int tid = threadIdx.x;
  __shared__ float km[1024];
  __shared__ float vm[4096];
  __shared__ float pr[4096];   // [tt][h][s]
  for (int i = tid; i < 1024; i += 256) km[i] = k_mem[(size_t)b * 1024 + i];
  for (int i = tid; i < 4096; i += 256) vm[i] = v_mem[(size_t)b * 4096 + i];
  __syncthreads();
  #pragma unroll
  for (int pi = 0; pi < 2; ++pi) {
    int p = pi * 256 + tid;
    int tt = p >> 3, hh = p & 7;
    int t = tc * 64 + tt;
    const u16* qrow = kq + ((size_t)(b * 1024 + t)) * 256 + 128 + hh * 16;
    float q[16];
    #pragma unroll
    for (int d = 0; d < 16; ++d) q[d] = b2f(qrow[d]);
    float s8[8]; float mx = -1e38f;
    #pragma unroll
    for (int s = 0; s < 8; ++s) {
      float a = 0.f;
      #pragma unroll
      for (int d = 0; d < 16; ++d) a += q[d] * km[s * 128 + hh * 16 + d];
      s8[s] = a; mx = fmaxf(mx, a);
    }
    float se = 0.f;
    #pragma unroll
    for (int s = 0; s < 8; ++s) { s8[s] = __expf(s8[s] - mx); se += s8[s]; }
    float inv = 1.f / se;
    #pragma unroll
    for (int s = 0; s < 8; ++s) pr[(tt * 8 + hh) * 8 + s] = s8[s] * inv;
  }
  __syncthreads();
  for (int oi = 0; oi < 128; ++oi) {
    int o = oi * 256 + tid;
    int tt = o >> 9, c = o & 511, hh = c >> 6;
    float a = 0.f;
    #pragma unroll
    for (int s = 0; s < 8; ++s) a += pr[(tt * 8 + hh) * 8 + s] * vm[s * 512 + c];
    int t = tc * 64 + tt;
    out[((size_t)t * 32 + b) * 512 + c] = a;
  }
}

extern "C" void kernel_launch(void* const* d_in, const int* in_sizes, int n_in,
                              void* d_out, int out_size, void* d_ws, size_t ws_size,
                              hipStream_t stream) {
  (void)in_sizes; (void)n_in; (void)out_size; (void)ws_size;
  const float* key   = (const float*)d_in[1];
  const float* memory= (const float*)d_in[2];
  const float* W_in  = (const float*)d_in[3];
  const float* b_in  = (const float*)d_in[4];
  const float* Wq    = (const float*)d_in[5];
  const float* bq    = (const float*)d_in[6];
  const float* Wk    = (const float*)d_in[7];
  const float* bk    = (const float*)d_in[8];
  const float* Wv    = (const float*)d_in[9];
  const float* bv    = (const float*)d_in[10];
  const float* W_mlp = (const float*)d_in[11];
  const float* b_mlp = (const float*)d_in[12];
  const float* g1    = (const float*)d_in[13];
  const float* be1   = (const float*)d_in[14];
  const float* g2    = (const float*)d_in[15];
  const float* be2   = (const float*)d_in[16];
  const float* w_rep = (const float*)d_in[17];
  const float* W_ig  = (const float*)d_in[18];
  const float* b_ig  = (const float*)d_in[19];
  const float* W_mg  = (const float*)d_in[20];
  const float* b_mg  = (const float*)d_in[21];
  const float* fbias = (const float*)d_in[22];
  const float* ibias = (const float*)d_in[23];
  float* out = (float*)d_out;

  char* p = (char*)d_ws;
  auto alloc = [&](size_t bytes) { char* r = p; p += (bytes + 255) & ~(size_t)255; return r; };
  u16* x       = (u16*)alloc(33554432);    // x bf16 (B,T,E)
  u16* kq      = (u16*)alloc(16777216);    // [k | q] bf16 (B*T, 256)
  u16* WinT    = (u16*)alloc(524288);
  u16* WkqT    = (u16*)alloc(262144);
  u16* WvT     = (u16*)alloc(524288);
  float* bkq   = (float*)alloc(1024);
  float* gpart = (float*)alloc(524288);    // (B, 8, 512)
  float* gi    = (float*)alloc(131072);
  float* gm    = (float*)alloc(1048576);
  float* att   = (float*)alloc(524288);
  float* nm_ln = (float*)alloc(524288);
  float* nmem  = (float*)alloc(524288);
  float* kmem  = (float*)alloc(131072);
  float* vmem  = (float*)alloc(524288);
  float* tm    = (float*)alloc(524288);
  float* qmw   = (float*)alloc(131072);    // (B, 8, 128)
  float* p3    = (float*)alloc(32768);     // (B, H, S, 4)
  int*   idx3  = (int*)alloc(24576);       // (B, H, S, 3)
  u16* XW      = (u16*)alloc(2097152);     // (H, 256, 512) bf16

  k_prep<<<3072, 256, 0, stream>>>(W_in, WinT, Wk, Wq, bk, bq, WkqT, bkq, Wv, WvT, memory, tm);
  gemm_kernel<1><<<dim3(256, 4), 256, 0, stream>>>(key, WinT, b_in, x, 32768, 512, 512);
  gemm_kernel<0><<<dim3(256, 2), 256, 0, stream>>>(x, WkqT, bkq, kq, 32768, 256, 512);
  k_qm<<<dim3(32, 8), 256, 0, stream>>>(memory, Wq, bq, qmw);
  k_scores_topk<<<dim3(32, 8, 8), 256, 0, stream>>>(qmw, kq, p3, idx3);
  k_xw<<<dim3(32, 8), 256, 0, stream>>>(x, p3, idx3, XW);
  k_attgemm<<<dim3(8, 2), 256, 0, stream>>>(XW, WvT, p3, bv, att);
  k_gipre<<<dim3(32, 8), 256, 0, stream>>>(x, w_rep, gpart);
  k_mem_lnmlp<<<dim3(32, 8), 256, 0, stream>>>(memory, att, g1, be1, W_mlp, b_mlp, g2, be2, nm_ln);
  k_gi_kernel<<<dim3(32, 4), 256, 0, stream>>>(gpart, W_ig, b_ig, gi);
  k_gm_kernel<<<dim3(8, 4, 4), 256, 0, stream>>>(tm, W_mg, b_mg, gm);
  k_gate_kernel<<<512, 256, 0, stream>>>(gi, gm, nm_ln, memory, fbias, ibias, nmem);
  k_kvmem_kernel<<<dim3(32, 10), 256, 0, stream>>>(nmem, Wk, bk, Wv, bv, kmem, vmem);
  k_out_attn<<<dim3(32, 16), 256, 0, stream>>>(kq, kmem, vmem, out);
}